// Round 6
// baseline (129.747 us; speedup 1.0000x reference)
//
#include <hip/hip_runtime.h>

// SigScale: out[b, off_k + n] = x[b, off_k + n] * prod_{j} y[b, digit_j(n)]
// B=256, D=8, M=6, siglen = 299592 floats/row. Memory-bound (~614 MB HBM).
// Row byte pitch 1198368 ≡ 32 (mod 128) -> per-row quad phase s = (-2b)&7
// makes bulk float4 wave accesses 128B-aligned.
// R6: SINGLE-VARIABLE ablation vs R5 — all nontemporal hints removed.
//     Everything else identical (batch 4, 2-deep pipeline, lb(256,8), grid 8x256).

#define SIGLEN 299592
#define NQ     74898   // SIGLEN / 4

typedef float f4 __attribute__((ext_vector_type(4)));

__device__ __forceinline__ float quad_g(int q,
                                        const float* __restrict__ f1,
                                        const float* __restrict__ f2,
                                        const float* __restrict__ f3,
                                        int& nout) {
    const int pos = q << 2;   // float index within the row
    int n; float g;
    if (pos >= 37448) {            // level 6: prefix p = n>>3 has 15 bits
        n = pos - 37448; const int p = n >> 3; g = f3[p >> 6] * f2[p & 63];
    } else if (pos >= 4680) {      // level 5: prefix 12 bits
        n = pos - 4680;  const int p = n >> 3; g = f3[p >> 3] * f1[p & 7];
    } else if (pos >= 584) {       // level 4: prefix 9 bits
        n = pos - 584;   g = f3[n >> 3];
    } else if (pos >= 72) {        // level 3
        n = pos - 72;    g = f2[n >> 3];
    } else if (pos >= 8) {         // level 2
        n = pos - 8;     g = f1[n >> 3];
    } else {                       // level 1
        n = pos;         g = 1.0f;
    }
    nout = n;
    return g;
}

__global__ __launch_bounds__(256, 8) void sigscale_kernel(
    const float* __restrict__ x,
    const float* __restrict__ y,
    float* __restrict__ out)
{
    __shared__ __align__(16) float f1[8];   // y
    __shared__ float f2[64];                // y⊗y
    __shared__ float f3[512];               // y⊗y⊗y

    const int b   = blockIdx.y;
    const int tid = threadIdx.x;

    if (tid < 8) f1[tid] = y[b * 8 + tid];
    __syncthreads();
    if (tid < 64) f2[tid] = f1[tid >> 3] * f1[tid & 7];
    __syncthreads();
    for (int i = tid; i < 512; i += 256) f3[i] = f2[i >> 3] * f1[i & 7];
    __syncthreads();

    // low-digit factors in registers (no LDS read needed for the last digit)
    const f4 ylo = *reinterpret_cast<const f4*>(&f1[0]);
    const f4 yhi = *reinterpret_cast<const f4*>(&f1[4]);

    const f4* __restrict__ xr   = reinterpret_cast<const f4*>(x + (size_t)b * SIGLEN);
    f4* __restrict__       orow = reinterpret_cast<f4*>(out + (size_t)b * SIGLEN);

    // phase shift so bulk accesses are 128B-aligned: (32*b + 16*s) % 128 == 0
    const int s = (-(b << 1)) & 7;

    // head quads [0, s) — levels 1..2 only, handled by block x==0
    if (blockIdx.x == 0 && tid < s) {
        const int q = tid;
        int n; const float g = quad_g(q, f1, f2, f3, n);
        const f4 yl = (n & 4) ? yhi : ylo;
        orow[q] = xr[q] * (g * yl);
    }

    constexpr int STRIDE = 2048;          // 8 blocks x 256 threads per row
    constexpr int BATCH  = 4;
    constexpr int SPAN   = BATCH * STRIDE;

    int q = s + blockIdx.x * 256 + tid;

    // 2-deep pipeline: loads for batch i+1 issue before stores of batch i.
    f4 v[BATCH];
    bool have = (q + (BATCH - 1) * STRIDE) < NQ;
    if (have) {
        #pragma unroll
        for (int j = 0; j < BATCH; ++j)
            v[j] = xr[q + j * STRIDE];
    }
    while (have) {
        const int qn = q + SPAN;
        const bool have_next = (qn + (BATCH - 1) * STRIDE) < NQ;
        f4 w[BATCH];
        if (have_next) {
            #pragma unroll
            for (int j = 0; j < BATCH; ++j)
                w[j] = xr[qn + j * STRIDE];
        }
        #pragma unroll
        for (int j = 0; j < BATCH; ++j) {
            int n; const float g = quad_g(q + j * STRIDE, f1, f2, f3, n);
            const f4 a = (n & 4) ? yhi : ylo;
            orow[q + j * STRIDE] = v[j] * (g * a);
        }
        if (have_next) {
            #pragma unroll
            for (int j = 0; j < BATCH; ++j) v[j] = w[j];
        }
        q = qn;
        have = have_next;
    }

    // tail singles
    for (; q < NQ; q += STRIDE) {
        int n; const float g = quad_g(q, f1, f2, f3, n);
        const f4 yl = (n & 4) ? yhi : ylo;
        orow[q] = xr[q] * (g * yl);
    }
}

extern "C" void kernel_launch(void* const* d_in, const int* in_sizes, int n_in,
                              void* d_out, int out_size, void* d_ws, size_t ws_size,
                              hipStream_t stream) {
    const float* x = (const float*)d_in[0];
    const float* y = (const float*)d_in[1];
    float* out = (float*)d_out;

    dim3 grid(8, 256);   // 2048 blocks = 8 blocks/CU, exactly resident
    sigscale_kernel<<<grid, 256, 0, stream>>>(x, y, out);
}

// Round 7
// 120.892 us; speedup vs baseline: 1.0732x; 1.0732x over previous
//
#include <hip/hip_runtime.h>

// SigScale: out[b, off_k + n] = x[b, off_k + n] * prod_{j} y[b, digit_j(n)]
// B=256, D=8, M=6, siglen = 299592 floats/row. Memory-bound (~614 MB HBM).
// Row byte pitch 1198368 ≡ 32 (mod 128) -> per-row quad phase s = (-2b)&7.
// R7: GEOMETRY change vs R5 — each block owns a CONTIGUOUS segment of its row
//     (9360 quads = 146.25 KB, boundaries kept ≡ s mod 8 for 128B alignment);
//     batch elements 256 quads (4 KB) apart -> one batch = contiguous 16 KB
//     per block. NT load+store, batch 4, lb(256,8), grid 8x256 all kept.

#define SIGLEN 299592
#define NQ     74898   // SIGLEN / 4
#define SEGQ   9360    // quads per block segment (multiple of 8; 8*9360=74880, rest -> block 7)

typedef float f4 __attribute__((ext_vector_type(4)));

__device__ __forceinline__ float quad_g(int q,
                                        const float* __restrict__ f1,
                                        const float* __restrict__ f2,
                                        const float* __restrict__ f3,
                                        int& nout) {
    const int pos = q << 2;   // float index within the row
    int n; float g;
    if (pos >= 37448) {            // level 6: prefix p = n>>3 has 15 bits
        n = pos - 37448; const int p = n >> 3; g = f3[p >> 6] * f2[p & 63];
    } else if (pos >= 4680) {      // level 5: prefix 12 bits
        n = pos - 4680;  const int p = n >> 3; g = f3[p >> 3] * f1[p & 7];
    } else if (pos >= 584) {       // level 4: prefix 9 bits
        n = pos - 584;   g = f3[n >> 3];
    } else if (pos >= 72) {        // level 3
        n = pos - 72;    g = f2[n >> 3];
    } else if (pos >= 8) {         // level 2
        n = pos - 8;     g = f1[n >> 3];
    } else {                       // level 1
        n = pos;         g = 1.0f;
    }
    nout = n;
    return g;
}

__global__ __launch_bounds__(256, 8) void sigscale_kernel(
    const float* __restrict__ x,
    const float* __restrict__ y,
    float* __restrict__ out)
{
    __shared__ __align__(16) float f1[8];   // y
    __shared__ float f2[64];                // y⊗y
    __shared__ float f3[512];               // y⊗y⊗y

    const int b   = blockIdx.y;
    const int tid = threadIdx.x;

    if (tid < 8) f1[tid] = y[b * 8 + tid];
    __syncthreads();
    if (tid < 64) f2[tid] = f1[tid >> 3] * f1[tid & 7];
    __syncthreads();
    for (int i = tid; i < 512; i += 256) f3[i] = f2[i >> 3] * f1[i & 7];
    __syncthreads();

    // low-digit factors in registers (no LDS read needed for the last digit)
    const f4 ylo = *reinterpret_cast<const f4*>(&f1[0]);
    const f4 yhi = *reinterpret_cast<const f4*>(&f1[4]);

    const f4* __restrict__ xr   = reinterpret_cast<const f4*>(x + (size_t)b * SIGLEN);
    f4* __restrict__       orow = reinterpret_cast<f4*>(out + (size_t)b * SIGLEN);

    // phase shift so bulk accesses are 128B-aligned: (32*b + 16*s) % 128 == 0
    const int s = (-(b << 1)) & 7;

    // head quads [0, s) — levels 1..2 only, handled by block x==0
    if (blockIdx.x == 0 && tid < s) {
        const int q = tid;
        int n; const float g = quad_g(q, f1, f2, f3, n);
        const f4 yl = (n & 4) ? yhi : ylo;
        orow[q] = xr[q] * (g * yl);
    }

    // contiguous per-block segment [segb, sege), base ≡ s (mod 8)
    const int segb = s + blockIdx.x * SEGQ;
    const int sege = (blockIdx.x == 7) ? NQ : segb + SEGQ;

    constexpr int STRIDE = 256;           // block-wide step (4 KB)
    constexpr int BATCH  = 4;
    constexpr int SPAN   = BATCH * STRIDE; // 1024 quads = 16 KB contiguous per batch

    int q = segb + tid;

    // main loop: 4 NT loads (16 KB contiguous per block), then 4 NT stores
    for (; q + (BATCH - 1) * STRIDE < sege; q += SPAN) {
        f4 v[BATCH];
        #pragma unroll
        for (int j = 0; j < BATCH; ++j)
            v[j] = __builtin_nontemporal_load(&xr[q + j * STRIDE]);
        #pragma unroll
        for (int j = 0; j < BATCH; ++j) {
            int n; const float g = quad_g(q + j * STRIDE, f1, f2, f3, n);
            const f4 a = (n & 4) ? yhi : ylo;
            __builtin_nontemporal_store(v[j] * (g * a), &orow[q + j * STRIDE]);
        }
    }

    // tail singles
    for (; q < sege; q += STRIDE) {
        int n; const float g = quad_g(q, f1, f2, f3, n);
        const f4 yl = (n & 4) ? yhi : ylo;
        const f4 t = __builtin_nontemporal_load(&xr[q]);
        __builtin_nontemporal_store(t * (g * yl), &orow[q]);
    }
}

extern "C" void kernel_launch(void* const* d_in, const int* in_sizes, int n_in,
                              void* d_out, int out_size, void* d_ws, size_t ws_size,
                              hipStream_t stream) {
    const float* x = (const float*)d_in[0];
    const float* y = (const float*)d_in[1];
    float* out = (float*)d_out;

    dim3 grid(8, 256);   // 2048 blocks = 8 blocks/CU, exactly resident
    sigscale_kernel<<<grid, 256, 0, stream>>>(x, y, out);
}

// Round 8
// 119.387 us; speedup vs baseline: 1.0868x; 1.0126x over previous
//
#include <hip/hip_runtime.h>

// SigScale: out[b, off_k + n] = x[b, off_k + n] * prod_{j} y[b, digit_j(n)]
// B=256, D=8, M=6, siglen = 299592 floats/row. Memory-bound (~614 MB HBM).
// Row byte pitch 1198368 ≡ 32 (mod 128) -> per-row quad phase s = (-2b)&7.
// R8: single variable vs R7 — grid.x 8 -> 4 (1024 blocks, 4/CU), SEGQ 18720.
//     Halves the number of concurrent DRAM streams (row-thrash hypothesis).
//     NT load+store, batch 4, contiguous block sweep, lb(256,8) all kept.

#define SIGLEN 299592
#define NQ     74898   // SIGLEN / 4
#define SEGQ   18720   // quads per block segment (multiple of 8; 4*18720=74880, rest -> last block)

typedef float f4 __attribute__((ext_vector_type(4)));

__device__ __forceinline__ float quad_g(int q,
                                        const float* __restrict__ f1,
                                        const float* __restrict__ f2,
                                        const float* __restrict__ f3,
                                        int& nout) {
    const int pos = q << 2;   // float index within the row
    int n; float g;
    if (pos >= 37448) {            // level 6: prefix p = n>>3 has 15 bits
        n = pos - 37448; const int p = n >> 3; g = f3[p >> 6] * f2[p & 63];
    } else if (pos >= 4680) {      // level 5: prefix 12 bits
        n = pos - 4680;  const int p = n >> 3; g = f3[p >> 3] * f1[p & 7];
    } else if (pos >= 584) {       // level 4: prefix 9 bits
        n = pos - 584;   g = f3[n >> 3];
    } else if (pos >= 72) {        // level 3
        n = pos - 72;    g = f2[n >> 3];
    } else if (pos >= 8) {         // level 2
        n = pos - 8;     g = f1[n >> 3];
    } else {                       // level 1
        n = pos;         g = 1.0f;
    }
    nout = n;
    return g;
}

__global__ __launch_bounds__(256, 8) void sigscale_kernel(
    const float* __restrict__ x,
    const float* __restrict__ y,
    float* __restrict__ out)
{
    __shared__ __align__(16) float f1[8];   // y
    __shared__ float f2[64];                // y⊗y
    __shared__ float f3[512];               // y⊗y⊗y

    const int b   = blockIdx.y;
    const int tid = threadIdx.x;

    if (tid < 8) f1[tid] = y[b * 8 + tid];
    __syncthreads();
    if (tid < 64) f2[tid] = f1[tid >> 3] * f1[tid & 7];
    __syncthreads();
    for (int i = tid; i < 512; i += 256) f3[i] = f2[i >> 3] * f1[i & 7];
    __syncthreads();

    // low-digit factors in registers (no LDS read needed for the last digit)
    const f4 ylo = *reinterpret_cast<const f4*>(&f1[0]);
    const f4 yhi = *reinterpret_cast<const f4*>(&f1[4]);

    const f4* __restrict__ xr   = reinterpret_cast<const f4*>(x + (size_t)b * SIGLEN);
    f4* __restrict__       orow = reinterpret_cast<f4*>(out + (size_t)b * SIGLEN);

    // phase shift so bulk accesses are 128B-aligned: (32*b + 16*s) % 128 == 0
    const int s = (-(b << 1)) & 7;

    // head quads [0, s) — levels 1..2 only, handled by block x==0
    if (blockIdx.x == 0 && tid < s) {
        const int q = tid;
        int n; const float g = quad_g(q, f1, f2, f3, n);
        const f4 yl = (n & 4) ? yhi : ylo;
        orow[q] = xr[q] * (g * yl);
    }

    // contiguous per-block segment [segb, sege), base ≡ s (mod 8)
    const int segb = s + blockIdx.x * SEGQ;
    const int sege = (blockIdx.x == 3) ? NQ : segb + SEGQ;

    constexpr int STRIDE = 256;           // block-wide step (4 KB)
    constexpr int BATCH  = 4;
    constexpr int SPAN   = BATCH * STRIDE; // 1024 quads = 16 KB contiguous per batch

    int q = segb + tid;

    // main loop: 4 NT loads (16 KB contiguous per block), then 4 NT stores
    for (; q + (BATCH - 1) * STRIDE < sege; q += SPAN) {
        f4 v[BATCH];
        #pragma unroll
        for (int j = 0; j < BATCH; ++j)
            v[j] = __builtin_nontemporal_load(&xr[q + j * STRIDE]);
        #pragma unroll
        for (int j = 0; j < BATCH; ++j) {
            int n; const float g = quad_g(q + j * STRIDE, f1, f2, f3, n);
            const f4 a = (n & 4) ? yhi : ylo;
            __builtin_nontemporal_store(v[j] * (g * a), &orow[q + j * STRIDE]);
        }
    }

    // tail singles
    for (; q < sege; q += STRIDE) {
        int n; const float g = quad_g(q, f1, f2, f3, n);
        const f4 yl = (n & 4) ? yhi : ylo;
        const f4 t = __builtin_nontemporal_load(&xr[q]);
        __builtin_nontemporal_store(t * (g * yl), &orow[q]);
    }
}

extern "C" void kernel_launch(void* const* d_in, const int* in_sizes, int n_in,
                              void* d_out, int out_size, void* d_ws, size_t ws_size,
                              hipStream_t stream) {
    const float* x = (const float*)d_in[0];
    const float* y = (const float*)d_in[1];
    float* out = (float*)d_out;

    dim3 grid(4, 256);   // 1024 blocks = 4 blocks/CU: halve concurrent DRAM streams
    sigscale_kernel<<<grid, 256, 0, stream>>>(x, y, out);
}